// Round 4
// baseline (516.242 us; speedup 1.0000x reference)
//
#include <hip/hip_runtime.h>

#define TDIM 2048
#define SEG 16
#define SEGLEN 128

typedef __attribute__((ext_vector_type(8))) short short8;
typedef __attribute__((ext_vector_type(4))) short short4v;
typedef __attribute__((ext_vector_type(4))) float float4v;

__device__ __forceinline__ float sigf(float x) { return 1.0f / (1.0f + __expf(-x)); }

__device__ __forceinline__ unsigned short f2bf_rne(float f) {
    unsigned u = __float_as_uint(f);
    unsigned r = (u + 0x7fffu + ((u >> 16) & 1u)) >> 16;
    return (unsigned short)r;
}
__device__ __forceinline__ float bf2f(unsigned short h) {
    return __uint_as_float(((unsigned)h) << 16);
}
struct bfpair { short hi, lo; };
__device__ __forceinline__ bfpair cvt_split(float x) {
    bfpair p;
    unsigned short h = f2bf_rne(x);
    p.hi = (short)h;
    p.lo = (short)f2bf_rne(x - bf2f(h));
    return p;
}

// fast split via v_cvt_pk_bf16_f32 (RNE, bit-identical to f2bf_rne)
__device__ __forceinline__ void split4_fast(float4 v, short4v& hi, short4v& lo) {
    unsigned h01, h23;
    asm("v_cvt_pk_bf16_f32 %0, %1, %2" : "=v"(h01) : "v"(v.x), "v"(v.y));
    asm("v_cvt_pk_bf16_f32 %0, %1, %2" : "=v"(h23) : "v"(v.z), "v"(v.w));
    float rx = v.x - __uint_as_float(h01 << 16);
    float ry = v.y - __uint_as_float(h01 & 0xffff0000u);
    float rz = v.z - __uint_as_float(h23 << 16);
    float rw = v.w - __uint_as_float(h23 & 0xffff0000u);
    unsigned l01, l23;
    asm("v_cvt_pk_bf16_f32 %0, %1, %2" : "=v"(l01) : "v"(rx), "v"(ry));
    asm("v_cvt_pk_bf16_f32 %0, %1, %2" : "=v"(l23) : "v"(rz), "v"(rw));
    union { unsigned u[2]; short4v s; } uh, ul;
    uh.u[0] = h01; uh.u[1] = h23;
    ul.u[0] = l01; ul.u[1] = l23;
    hi = uh.s; lo = ul.s;
}

// DPP 16-lane butterfly sum (== shfl_xor 1/2/4/8 tree)
template<int CTRL>
__device__ __forceinline__ float dpp_addt(float v) {
    int t = __builtin_amdgcn_update_dpp(0, __float_as_int(v), CTRL, 0xf, 0xf, true);
    return v + __int_as_float(t);
}
__device__ __forceinline__ float red16d(float v) {
    v = dpp_addt<0xB1>(v);
    v = dpp_addt<0x4E>(v);
    v = dpp_addt<0x141>(v);
    v = dpp_addt<0x140>(v);
    return v;
}

__device__ __forceinline__ float dot4f(float4 a, float4 b) {
    return fmaf(a.w, b.w, fmaf(a.z, b.z, fmaf(a.y, b.y, a.x * b.x)));
}
__device__ __forceinline__ float red4g(float v) {
    v += __shfl_xor(v, 16);
    v += __shfl_xor(v, 32);
    return v;
}

// async global->LDS 16B copy; LDS dest is wave-uniform base + lane*16.
__device__ __forceinline__ void gld16(const void* g, void* l) {
    __builtin_amdgcn_global_load_lds(
        (const __attribute__((address_space(1))) unsigned*)g,
        (__attribute__((address_space(3))) unsigned*)l, 16, 0, 0);
}

// ---------------------------------------------------------------------------
// prep_w: pre-split W (200x256, zero-pad to 208 rows) into SWIZZLED image:
// [kc][row][unit_sw], unit_sw = (2*gg) ^ (row&7)  (hi), ^1 (lo).
// Swizzle never crosses bit3, so units 0..7 of a row = k-groups 0..3 exactly:
// half-kc slabs are the contiguous unit ranges [0,8) and [8,16).
// ---------------------------------------------------------------------------
__global__ __launch_bounds__(256) void prep_w_kernel(
    const float* __restrict__ Wq, const float* __restrict__ Wk, const float* __restrict__ Wv,
    const float* __restrict__ Wbw, const float* __restrict__ Waw,
    short* __restrict__ wimg)
{
    int u = blockIdx.x * 256 + threadIdx.x;
    if (u >= 6656) return;
    int kc = u / 1664, rem = u % 1664;
    int rr = rem >> 3, gg = rem & 7;
    const float* wrow = nullptr;
    if (rr < 64)       wrow = Wq  + (size_t)rr * 256;
    else if (rr < 128) wrow = Wk  + (size_t)(rr - 64) * 256;
    else if (rr < 192) wrow = Wv  + (size_t)(rr - 128) * 256;
    else if (rr < 196) wrow = Wbw + (size_t)(rr - 192) * 256;
    else if (rr < 200) wrow = Waw + (size_t)(rr - 196) * 256;
    int usw = (2 * gg) ^ (rr & 7);
    short* dh = wimg + ((size_t)kc * 3328 + rr * 16 + usw) * 8;
    short* dl = wimg + ((size_t)kc * 3328 + rr * 16 + (usw ^ 1)) * 8;
#pragma unroll
    for (int s = 0; s < 8; ++s) {
        float v = wrow ? wrow[kc * 64 + gg * 8 + s] : 0.0f;
        bfpair p = cvt_split(v);
        dh[s] = p.hi; dl[s] = p.lo;
    }
}

// prep_ow: out_w (192x64) -> swizzled image [row][unit_sw], 3072 units.
__global__ __launch_bounds__(256) void prep_ow_kernel(
    const float* __restrict__ ow, short* __restrict__ owimg)
{
    int u = blockIdx.x * 256 + threadIdx.x;
    if (u >= 1536) return;
    int rr = u >> 3, gg = u & 7;
    int usw = (2 * gg) ^ (rr & 7);
    short* dh = owimg + ((size_t)rr * 16 + usw) * 8;
    short* dl = owimg + ((size_t)rr * 16 + (usw ^ 1)) * 8;
#pragma unroll
    for (int s = 0; s < 8; ++s) {
        bfpair p = cvt_split(ow[(size_t)rr * 64 + gg * 8 + s]);
        dh[s] = p.hi; dl[s] = p.lo;
    }
}

// ---------------------------------------------------------------------------
// Kernel A: fused projection GEMM + LN/L2norm/sigmoid epilogue.
// Half-kc (32-k) staging slabs: wsh 26KB + xsh 8KB = 34.8KB/block ->
// 4 blocks/CU (16 waves) instead of 2. 8 half-chunks, one ks each.
// W staged async (global_load_lds of the pre-swizzled image), X reg-prefetch
// across a raw s_barrier with counted vmcnt(2).
// ---------------------------------------------------------------------------
__global__ __launch_bounds__(256, 4) void proj_kernel(
    const float* __restrict__ x, const float* __restrict__ curv, const float* __restrict__ ent,
    const short* __restrict__ wimg,
    const float* __restrict__ Wbb, const float* __restrict__ Wab,
    const float* __restrict__ cw, const float* __restrict__ ew,
    const float* __restrict__ lnqw, const float* __restrict__ lnqb,
    const float* __restrict__ lnkw, const float* __restrict__ lnkb,
    float* __restrict__ q_ws, float* __restrict__ k_ws, float* __restrict__ v_ws,
    float* __restrict__ beta_ws, float* __restrict__ alpha_ws)
{
    __shared__ __align__(16) short xsh[64 * 64];      // 64 rows x 8 units, 8KB
    __shared__ __align__(16) short wsh[1664 * 8];     // 208 rows x 8 units, 26KB

    const int tid = threadIdx.x;
    const int lane = tid & 63, wv = tid >> 6;
    const int i16 = lane & 15, gq = lane >> 4, swz = i16 & 7;
    const int row0 = blockIdx.x * 64;
    const int ntbase = (wv == 0) ? 0 : (1 + 3 * wv);   // 0,4,7,10
    const int ntcnt  = (wv == 0) ? 4 : 3;

    float4v acc[4][4];
#pragma unroll
    for (int m = 0; m < 4; ++m)
#pragma unroll
        for (int nI = 0; nI < 4; ++nI) acc[m][nI] = (float4v){0.f, 0.f, 0.f, 0.f};

    // initial X load (hc=0): 2 float4/thread covering 64 rows x 32 k
    float4 xr[2];
#pragma unroll
    for (int it = 0; it < 2; ++it) {
        int f = it * 256 + tid, rr = f >> 3, c4 = f & 7;
        xr[it] = *(const float4*)&x[(size_t)(row0 + rr) * 256 + c4 * 4];
    }

    for (int hc = 0; hc < 8; ++hc) {
        __builtin_amdgcn_s_barrier();            // previous MFMA done; LDS free
        // W half-slab async stage: 1664 units (7 guarded iters; 1664 = 26 waves)
        const short* wk = wimg + (size_t)(hc >> 1) * 26624;
        const int hoff = (hc & 1) * 8;
#pragma unroll
        for (int it = 0; it < 7; ++it) {
            int f = it * 256 + tid;
            if (f < 1664) {
                int rr = f >> 3, uu = f & 7;
                gld16(wk + ((size_t)rr * 16 + hoff + uu) * 8, &wsh[f * 8]);
            }
        }
        asm volatile("" ::: "memory");
        // X convert for current half (xr resident)
#pragma unroll
        for (int it = 0; it < 2; ++it) {
            int f = it * 256 + tid, rr = f >> 3, c4 = f & 7;
            short4v hi, lo;
            split4_fast(xr[it], hi, lo);
            int usw = (2 * (c4 >> 1)) ^ (rr & 7);
            *(short4v*)&xsh[rr * 64 + usw * 8 + (c4 & 1) * 4] = hi;
            *(short4v*)&xsh[rr * 64 + (usw ^ 1) * 8 + (c4 & 1) * 4] = lo;
        }
        // prefetch next half's X (stays in flight across the barrier)
        if (hc < 7) {
#pragma unroll
            for (int it = 0; it < 2; ++it) {
                int f = it * 256 + tid, rr = f >> 3, c4 = f & 7;
                xr[it] = *(const float4*)&x[(size_t)(row0 + rr) * 256 + (hc + 1) * 32 + c4 * 4];
            }
            asm volatile("s_waitcnt vmcnt(2) lgkmcnt(0)" ::: "memory");
        } else {
            asm volatile("s_waitcnt vmcnt(0) lgkmcnt(0)" ::: "memory");
        }
        __builtin_amdgcn_s_barrier();
        // MFMA phase: one ks (g4 = gq) per half-chunk
        const int uA = ((2 * gq) ^ swz) * 8;
        short8 ah[4], al[4];
#pragma unroll
        for (int m = 0; m < 4; ++m) {
            const int rb = (m * 16 + i16) * 64;
            ah[m] = *(const short8*)&xsh[rb + uA];
            al[m] = *(const short8*)&xsh[rb + (uA ^ 8)];
        }
#pragma unroll
        for (int nI = 0; nI < 4; ++nI) if (nI < ntcnt) {
            const int rowB = ((ntbase + nI) * 16 + i16) * 64;
            short8 bh = *(const short8*)&wsh[rowB + uA];
            short8 bl = *(const short8*)&wsh[rowB + (uA ^ 8)];
#pragma unroll
            for (int m = 0; m < 4; ++m) {
                acc[m][nI] = __builtin_amdgcn_mfma_f32_16x16x32_bf16(ah[m], bh, acc[m][nI], 0, 0, 0);
                acc[m][nI] = __builtin_amdgcn_mfma_f32_16x16x32_bf16(ah[m], bl, acc[m][nI], 0, 0, 0);
                acc[m][nI] = __builtin_amdgcn_mfma_f32_16x16x32_bf16(al[m], bh, acc[m][nI], 0, 0, 0);
            }
        }
    }

    // Epilogue. C/D layout: col = lane&15, row = (lane>>4)*4 + reg.
    const int c = i16;
    const float lnqw_c = lnqw[c], lnqb_c = lnqb[c];
    const float lnkw_c = lnkw[c], lnkb_c = lnkb[c];
    const int nblk = row0 >> 11;
    const float Kv = fminf(fabsf(curv[nblk >> 4]), 10.0f);
    const float Sv = fminf(fmaxf(ent[nblk >> 4], 0.0f), 5.0f);
#pragma unroll
    for (int nI = 0; nI < 4; ++nI) if (nI < ntcnt) {
        const int nt = ntbase + nI;
#pragma unroll
        for (int m = 0; m < 4; ++m) {
#pragma unroll
            for (int j = 0; j < 4; ++j) {
                const int grow = row0 + m * 16 + gq * 4 + j;
                const int n = grow >> 11, t = grow & 2047;
                float y = acc[m][nI][j];
                if (nt < 4) {
                    float s = red16d(y), s2 = red16d(y * y);
                    float mean = s * 0.0625f;
                    float var = s2 * 0.0625f - mean * mean;
                    float inv = rsqrtf(var + 1e-5f);
                    q_ws[((size_t)(n * 4 + nt) * TDIM + t) * 16 + c] = (y - mean) * inv * lnqw_c + lnqb_c;
                } else if (nt < 8) {
                    float s = red16d(y), s2 = red16d(y * y);
                    float mean = s * 0.0625f;
                    float var = s2 * 0.0625f - mean * mean;
                    float inv = rsqrtf(var + 1e-5f);
                    float kn = (y - mean) * inv * lnkw_c + lnkb_c;
                    float s3 = red16d(kn * kn);
                    kn = kn / fmaxf(sqrtf(s3), 1e-12f);
                    k_ws[((size_t)(n * 4 + (nt - 4)) * TDIM + t) * 16 + c] = kn;
                } else if (nt < 12) {
                    v_ws[((size_t)(n * 4 + (nt - 8)) * TDIM + t) * 16 + c] = y;
                } else {
                    if (c < 4)
                        beta_ws[(size_t)(n * 4 + c) * TDIM + t] = sigf(sigf(y + Wbb[c]) + Kv * cw[c]);
                    else if (c < 8) {
                        int h = c - 4;
                        alpha_ws[(size_t)(n * 4 + h) * TDIM + t] = sigf(sigf(y + Wab[h]) + Sv * ew[h]);
                    }
                }
            }
        }
    }
}

// ---------------------------------------------------------------------------
// Segmented scan (unchanged, verified).
// ---------------------------------------------------------------------------
__global__ __launch_bounds__(64) void scan_p1_kernel(
    const float* __restrict__ k_ws, const float* __restrict__ v_ws,
    const float* __restrict__ beta_ws, const float* __restrict__ alpha_ws,
    float* __restrict__ pq_ws)
{
    __shared__ __align__(16) float ks[128 * 16], bvs[128 * 16];
    __shared__ __align__(16) float tb1[128 * 4];
    const int tid = threadIdx.x;
    const int sid = blockIdx.x;     // 0..14
    const int cid = blockIdx.y;     // 0..255
    const int i = tid & 15, g = tid >> 4;
    const int t0g = sid * SEGLEN;
    const float* kb = k_ws + ((size_t)cid * TDIM + t0g) * 16;
    const float* vb = v_ws + ((size_t)cid * TDIM + t0g) * 16;
    const float* bb = beta_ws + (size_t)cid * TDIM + t0g;
    const float* ab = alpha_ws + (size_t)cid * TDIM + t0g;

    for (int f = tid; f < 128 * 16; f += 64) { ks[f] = 0.f; bvs[f] = 0.f; }
    for (int f = tid; f < 128 * 4; f += 64) tb1[f] = 0.f;
    __syncthreads();

    float4 kr[4], vr[4]; float be = 0.f, alp = 0.f;
    auto load_stage = [&](int s) {
        size_t t0 = (size_t)s * 64 + tid;
        const float4* kp = (const float4*)(kb + t0 * 16);
        const float4* vp = (const float4*)(vb + t0 * 16);
#pragma unroll
        for (int j = 0; j < 4; ++j) { kr[j] = kp[j]; vr[j] = vp[j]; }
        be = bb[t0]; alp = ab[t0];
    };
    auto commit_stage = [&](int s) {
        int r = (s & 1) * 64 + tid;
#pragma unroll
        for (int j = 0; j < 4; ++j) {
            *(float4*)&ks[r * 16 + 4 * j] = kr[j];
            float4 bv4 = make_float4(be * vr[j].x, be * vr[j].y, be * vr[j].z, be * vr[j].w);
            *(float4*)&bvs[r * 16 + 4 * j] = bv4;
        }
    };
    auto table_pass = [&](int s) {
        int r0 = (s & 1) * 64 + tid;
        int rm1 = (r0 - 1) & 127, rm2 = (r0 - 2) & 127;
        float C = 0.f, C2 = 0.f;
#pragma unroll
        for (int j = 0; j < 4; ++j) {
            float4 kt  = *(float4*)&ks[r0 * 16 + 4 * j];
            float4 km1 = *(float4*)&ks[rm1 * 16 + 4 * j];
            float4 km2 = *(float4*)&ks[rm2 * 16 + 4 * j];
            C  += dot4f(km1, kt);
            C2 += dot4f(km2, kt);
        }
        *(float4*)&tb1[r0 * 4] = make_float4(alp * C, alp * C2, alp, 0.f);
    };

    load_stage(0);
    commit_stage(0);
    __syncthreads();
    table_pass(0);
    __syncthreads();

    float4 Q4 = make_float4(0.f, 0.f, 0.f, 0.f);
    float4 P4 = make_float4(i == 4 * g + 0 ? 1.f : 0.f,
                            i == 4 * g + 1 ? 1.f : 0.f,
                            i == 4 * g + 2 ? 1.f : 0.f,
                            i == 4 * g + 3 ? 1.f : 0.f);
    float wq1 = 0.f, wq2 = 0.f, wp1 = 0.f, wp2 = 0.f;
    float4 k4m1 = make_float4(0.f, 0.f, 0.f, 0.f);
    float4 k4_0 = *(float4*)&ks[0 * 16 + 4 * g];
    float4 k4p1 = *(float4*)&ks[1 * 16 + 4 * g];
    float upQ_cur = 0.f;
    float upP_cur = ks[i];
    float4 ta0 = *(float4*)&tb1[0];
    float aC1_c = ta0.x, aC2_c = ta0.y, al_c = ta0.z;
    float bv_c = bvs[i];

    int t = 0;
    auto step = [&]() {
        int rp2 = (t + 2) & 127, rp1 = (t + 1) & 127;
        float4 k4in = *(float4*)&ks[rp2 * 16 + 4 * g];
        float4 tain = *(float4*)&tb1[rp1 * 4];
        float bvin = bvs[rp1 * 16 + i];
        float upQ = red4g(dot4f(Q4, k4p1));
        float upP = red4g(dot4f(P4, k4p1));
        Q4.x = fmaf(wq1, k4m1.x, Q4.x);
        Q4.y = fmaf(wq1, k4m1.y, Q4.y);
        Q4.z = fmaf(wq1, k4m1.z, Q4.z);
        Q4.w = fmaf(wq1, k4m1.w, Q4.w);
        P4.x = fmaf(wp1, k4m1.x, P4.x);
        P4.y = fmaf(wp1, k4m1.y, P4.y);
        P4.z = fmaf(wp1, k4m1.z, P4.z);
        P4.w = fmaf(wp1, k4m1.w, P4.w);
        float rq = fmaf(-aC2_c, wq2, fmaf(-al_c, upQ_cur, bv_c));
        float wq0 = fmaf(-aC1_c, wq1, rq);
        float rp_ = fmaf(-aC2_c, wp2, -al_c * upP_cur);
        float wp0 = fmaf(-aC1_c, wp1, rp_);
        wq2 = wq1; wq1 = wq0; wp2 = wp1; wp1 = wp0;
        k4m1 = k4_0; k4_0 = k4p1; k4p1 = k4in;
        upQ_cur = upQ; upP_cur = upP;
        aC1_c = tain.x; aC2_c = tain.y; al_c = tain.z; bv_c = bvin;
        ++t;
    };

    load_stage(1);
#pragma unroll 4
    for (int u = 0; u < 32; ++u) step();
    commit_stage(1);
#pragma unroll 4
    for (int u = 0; u < 16; ++u) step();
    table_pass(1);
#pragma unroll 4
    for (int u = 0; u < 16; ++u) step();
#pragma unroll 4
    for (int u = 0; u < 64; ++u) step();

    Q4.x = fmaf(wq1, k4m1.x, Q4.x);
    Q4.y = fmaf(wq1, k4m1.y, Q4.y);
    Q4.z = fmaf(wq1, k4m1.z, Q4.z);
    Q4.w = fmaf(wq1, k4m1.w, Q4.w);
    P4.x = fmaf(wp1, k4m1.x, P4.x);
    P4.y = fmaf(wp1, k4m1.y, P4.y);
    P4.z = fmaf(wp1, k4m1.z, P4.z);
    P4.w = fmaf(wp1, k4m1.w, P4.w);

    float* dst = pq_ws + ((size_t)cid * 15 + sid) * 512;
    *(float4*)&dst[i * 16 + 4 * g] = Q4;
    *(float4*)&dst[256 + i * 16 + 4 * g] = P4;
}

__global__ __launch_bounds__(64) void scan_p2_kernel(
    const float* __restrict__ pq_ws, float* __restrict__ min_ws)
{
    __shared__ float Mlds[256], Plds[256];
    const int tid = threadIdx.x;
    const int cid = blockIdx.x;
    const int i = tid & 15, g = tid >> 4;
    float4 M4 = make_float4(0.f, 0.f, 0.f, 0.f);
    *(float4*)&min_ws[((size_t)cid * SEG + 0) * 256 + i * 16 + 4 * g] = M4;
    for (int sid = 0; sid < 15; ++sid) {
        const float* base = pq_ws + ((size_t)cid * 15 + sid) * 512;
        float4 Qn = *(const float4*)&base[i * 16 + 4 * g];
        float4 Pn = *(const float4*)&base[256 + i * 16 + 4 * g];
        *(float4*)&Mlds[i * 16 + 4 * g] = M4;
        *(float4*)&Plds[i * 16 + 4 * g] = Pn;
        __syncthreads();
        float4 acc = Qn;
#pragma unroll
        for (int m = 0; m < 16; ++m) {
            float mm = Mlds[i * 16 + m];
            float4 pr = *(float4*)&Plds[m * 16 + 4 * g];
            acc.x = fmaf(mm, pr.x, acc.x);
            acc.y = fmaf(mm, pr.y, acc.y);
            acc.z = fmaf(mm, pr.z, acc.z);
            acc.w = fmaf(mm, pr.w, acc.w);
        }
        M4 = acc;
        __syncthreads();
        *(float4*)&min_ws[((size_t)cid * SEG + sid + 1) * 256 + i * 16 + 4 * g] = M4;
    }
}

__global__ __launch_bounds__(64) void scan_p3_kernel(
    const float* __restrict__ q_ws, const float* __restrict__ k_ws, const float* __restrict__ v_ws,
    const float* __restrict__ beta_ws, const float* __restrict__ alpha_ws,
    const float* __restrict__ min_ws, float* __restrict__ o_ws)
{
    __shared__ __align__(16) float ks[128 * 16], qs[128 * 16], bvs[128 * 16];
    __shared__ __align__(16) float tbl[128 * 8];
    __shared__ __align__(16) float os[64 * 16];
    const int tid = threadIdx.x;
    const int sid = blockIdx.x;     // 0..15
    const int cid = blockIdx.y;     // 0..255
    const int i = tid & 15, g = tid >> 4;
    const int t0g = sid * SEGLEN;
    const float* kb = k_ws + ((size_t)cid * TDIM + t0g) * 16;
    const float* qb = q_ws + ((size_t)cid * TDIM + t0g) * 16;
    const float* vb = v_ws + ((size_t)cid * TDIM + t0g) * 16;
    const float* bb = beta_ws + (size_t)cid * TDIM + t0g;
    const float* ab = alpha_ws + (size_t)cid * TDIM + t0g;
    float* obp = o_ws + ((size_t)cid * TDIM + t0g) * 16;

    for (int f = tid; f < 128 * 16; f += 64) { ks[f] = 0.f; qs[f] = 0.f; bvs[f] = 0.f; }
    for (int f = tid; f < 128 * 8; f += 64) tbl[f] = 0.f;
    __syncthreads();

    float4 kr[4], qr[4], vr[4]; float be = 0.f, alp = 0.f;
    auto load_stage = [&](int s) {
        size_t t0 = (size_t)s * 64 + tid;
        const float4* kp = (const float4*)(kb + t0 * 16);
        const float4* qp = (const float4*)(qb + t0 * 16);
        const float4* vp = (const float4*)(vb + t0 * 16);
#pragma unroll
        for (int j = 0; j < 4; ++j) { kr[j] = kp[j]; qr[j] = qp[j]; vr[j] = vp[j]; }
        be = bb[t0]; alp = ab[t0];
    };
    auto commit_stage = [&](int s) {
        int r = (s & 1) * 64 + tid;
#pragma unroll
        for (int j = 0; j < 4; ++j) {
            *(float4*)&ks[r * 16 + 4 * j] = kr[j];
            *(float4*)&qs[r * 16 + 4 * j] = qr[j];
            float4 bv4 = make_float4(be * vr[j].x, be * vr[j].y, be * vr[j].z, be * vr[j].w);
            *(float4*)&bvs[r * 16 + 4 * j] = bv4;
        }
    };
    auto table_pass = [&](int s) {
        int r0 = (s & 1) * 64 + tid;
        int rm1 = (r0 - 1) & 127, rm2 = (r0 - 2) & 127;
        float C = 0.f, C2 = 0.f, d = 0.f, e = 0.f, E2 = 0.f;
#pragma unroll
        for (int j = 0; j < 4; ++j) {
            float4 kt  = *(float4*)&ks[r0 * 16 + 4 * j];
            float4 km1 = *(float4*)&ks[rm1 * 16 + 4 * j];
            float4 km2 = *(float4*)&ks[rm2 * 16 + 4 * j];
            float4 qt  = *(float4*)&qs[r0 * 16 + 4 * j];
            C  += dot4f(km1, kt);
            C2 += dot4f(km2, kt);
            d  += dot4f(kt,  qt);
            e  += dot4f(km1, qt);
            E2 += dot4f(km2, qt);
        }
        *(float4*)&tbl[r0 * 8] = make_float4(alp * C, alp * C2, d, e);
        *(float2*)&tbl[r0 * 8 + 4] = make_float2(E2, alp);
    };

    load_stage(0);
    commit_stage(0);
    __syncthreads();
    table_pass(0);
    __syncthreads();

    float4 M4 = *(const float4*)&min_ws[((size_t)cid * SEG + sid) * 256 + i * 16 + 4 * g];
    float w1 = 0.f, w2 = 0.f;
    float4 k4m1 = make_float4(0.f, 0.f, 0.f, 0.f);
    float4 k4_0 = *(float4*)&ks[0 * 16 + 4 * g];
    float4 q4_0 = *(float4*)&qs[0 * 16 + 4 * g];
    float4 k4p1 = *(float4*)&ks[1 * 16 + 4 * g];
    float4 q4p1 = *(float4*)&qs[1 * 16 + 4 * g];
    float up_cur = red4g(dot4f(M4, k4_0));
    float rp_cur = red4g(dot4f(M4, q4_0));
    float4 ta0 = *(float4*)&tbl[0];
    float aC1_c = ta0.x, aC2_c = ta0.y, d_c = ta0.z, e_c = ta0.w;
    float2 tx0 = *(float2*)&tbl[4];
    float E2_c = tx0.x, al_c = tx0.y;
    float bv_c = bvs[i];

    int t = 0;
    auto step = [&]() {
        int rp2 = (t + 2) & 127, rp1 = (t + 1) & 127;
        float4 k4in = *(float4*)&ks[rp2 * 16 + 4 * g];
        float4 q4in = *(float4*)&qs[rp2 * 16 + 4 * g];
        float4 tain = *(float4*)&tbl[rp1 * 8];
        float2 txin = *(float2*)&tbl[rp1 * 8 + 4];
        float bvin = bvs[rp1 * 16 + i];
        float up = red4g(dot4f(M4, k4p1));
        float rp = red4g(dot4f(M4, q4p1));
        M4.x = fmaf(w1, k4m1.x, M4.x);
        M4.y = fmaf(w1, k4m1.y, M4.y);
        M4.z = fmaf(w1, k4m1.z, M4.z);
        M4.w = fmaf(w1, k4m1.w, M4.w);
        float r = fmaf(-aC2_c, w2, fmaf(-al_c, up_cur, bv_c));
        float w0 = fmaf(-aC1_c, w1, r);
        float o = fmaf(w0, d_c, fmaf(w1, e_c, fmaf(w2, E2_c, rp_cur)));
        if (g == 0) os[(t & 63) * 16 + i] = o;
        w2 = w1; w1 = w0;
        k4m1 = k4_0; k4_0 = k4p1; k4p1 = k4in;
        q4p1 = q4in;
        up_cur = up; rp_cur = rp;
        aC1_c = tain.x; aC2_c = tain.y; d_c = tain.z; e_c = tain.w;
        E2_c = txin.x; al_c = txin.y; bv_c = bvin;
        ++t;
    };

    for (int s = 0; s < 2; ++s) {
        if (s == 0) load_stage(1);
#pragma unroll 4
        for (int u = 0; u < 32; ++u) step();
        if (s == 0) commit_stage(1);
#pragma unroll 4
        for (int u = 0; u < 16; ++u) step();
        if (s == 0) table_pass(1);
#pragma unroll 4
        for (int u = 0; u < 16; ++u) step();
#pragma unroll
        for (int j = 0; j < 4; ++j) {
            float4 ov = *(float4*)&os[(tid * 4 + j) * 4];
            *(float4*)&obp[(size_t)s * 1024 + (tid * 4 + j) * 4] = ov;
        }
    }
}

// ---------------------------------------------------------------------------
// Kernel C: output projection, half-K (32-k) slabs: wsh 24KB + osh 8KB =
// 32KB/block -> 5 blocks/CU. Structure mirrors proj.
// ---------------------------------------------------------------------------
__global__ __launch_bounds__(256, 4) void outproj_kernel(
    const float* __restrict__ o_ws, const short* __restrict__ owimg,
    const float* __restrict__ ob, float* __restrict__ out)
{
    __shared__ __align__(16) short osh[64 * 64];      // 8KB
    __shared__ __align__(16) short wsh[1536 * 8];     // 24KB
    const int tid = threadIdx.x;
    const int lane = tid & 63, wv = tid >> 6;
    const int i16 = lane & 15, gq = lane >> 4, swz = i16 & 7;
    const int row0 = blockIdx.x * 64;
    const int ntbase = wv * 3;

    float4v acc[4][3];
#pragma unroll
    for (int m = 0; m < 4; ++m)
#pragma unroll
        for (int nI = 0; nI < 3; ++nI) acc[m][nI] = (float4v){0.f, 0.f, 0.f, 0.f};

    // initial o load (half 0)
    float4 orr[2];
#pragma unroll
    for (int it = 0; it < 2; ++it) {
        int f = it * 256 + tid, rr = f >> 3, c4 = f & 7;
        int grow = row0 + rr;
        int n = grow >> 11, t = grow & 2047;
        int h = c4 >> 2, d4 = c4 & 3;
        orr[it] = *(const float4*)&o_ws[((size_t)(n * 4 + h) * TDIM + t) * 16 + d4 * 4];
    }

#pragma unroll
    for (int half = 0; half < 2; ++half) {
        __builtin_amdgcn_s_barrier();
        // W half-slab async stage: 1536 units = 6 iters
#pragma unroll
        for (int it = 0; it < 6; ++it) {
            int f = it * 256 + tid;
            int rr = f >> 3, uu = f & 7;
            gld16(owimg + ((size_t)rr * 16 + half * 8 + uu) * 8, &wsh[f * 8]);
        }
        asm volatile("" ::: "memory");
        // o convert current half
#pragma unroll
        for (int it = 0; it < 2; ++it) {
            int f = it * 256 + tid, rr = f >> 3, c4 = f & 7;
            short4v hi, lo;
            split4_fast(orr[it], hi, lo);
            int usw = (2 * (c4 >> 1)) ^ (rr & 7);
            *(short4v*)&osh[rr * 64 + usw * 8 + (c4 & 1) * 4] = hi;
            *(short4v*)&osh[rr * 64 + (usw ^ 1) * 8 + (c4 & 1) * 4] = lo;
        }
        if (half == 0) {
#pragma unroll
            for (int it = 0; it < 2; ++it) {
                int f = it * 256 + tid, rr = f >> 3, c4 = f & 7;
                int grow = row0 + rr;
                int n = grow >> 11, t = grow & 2047;
                int col = 32 + c4 * 4;
                int h = col >> 4, d4 = (col >> 2) & 3;
                orr[it] = *(const float4*)&o_ws[((size_t)(n * 4 + h) * TDIM + t) * 16 + d4 * 4];
            }
            asm volatile("s_waitcnt vmcnt(2) lgkmcnt(0)" ::: "memory");
        } else {
            asm volatile("s_waitcnt vmcnt(0) lgkmcnt(0)" ::: "memory");
        }
        __builtin_amdgcn_s_barrier();

        const int uA = ((2 * gq) ^ swz) * 8;
        short8 ah[4], al[4];
#pragma unroll
        for (int m = 0; m < 4; ++m) {
            const int rb = (m * 16 + i16) * 64;
            ah[m] = *(const short8*)&osh[rb + uA];
            al[m] = *(const short8*)&osh[rb + (uA ^ 8)];
        }
#pragma unroll
        for (int nI = 0; nI < 3; ++nI) {
            const int rowB = ((ntbase + nI) * 16 + i16) * 64;
            short8 bh = *(const short8*)&wsh[rowB + uA];
            short8 bl = *(const short8*)&wsh[rowB + (uA ^ 8)];
#pragma unroll
            for (int m = 0; m < 4; ++m) {
                acc[m][nI] = __builtin_amdgcn_mfma_f32_16x16x32_bf16(ah[m], bh, acc[m][nI], 0, 0, 0);
                acc[m][nI] = __builtin_amdgcn_mfma_f32_16x16x32_bf16(ah[m], bl, acc[m][nI], 0, 0, 0);
                acc[m][nI] = __builtin_amdgcn_mfma_f32_16x16x32_bf16(al[m], bh, acc[m][nI], 0, 0, 0);
            }
        }
    }

#pragma unroll
    for (int nI = 0; nI < 3; ++nI) {
        const int nt = ntbase + nI;
        const float bias = ob[nt * 16 + i16];
#pragma unroll
        for (int m = 0; m < 4; ++m) {
#pragma unroll
            for (int j = 0; j < 4; ++j) {
                int grow = row0 + m * 16 + gq * 4 + j;
                int n = grow >> 11, t = grow & 2047;
                int b = n >> 4, p = n & 15;
                out[((size_t)(b * TDIM + t) * 16 + p) * 192 + nt * 16 + i16] = acc[m][nI][j] + bias;
            }
        }
    }
}

extern "C" void kernel_launch(void* const* d_in, const int* in_sizes, int n_in,
                              void* d_out, int out_size, void* d_ws, size_t ws_size,
                              hipStream_t stream) {
    (void)in_sizes; (void)n_in; (void)out_size; (void)ws_size;
    const float* x    = (const float*)d_in[0];
    const float* curv = (const float*)d_in[1];
    const float* ent  = (const float*)d_in[2];
    const float* Wq   = (const float*)d_in[3];
    const float* Wk   = (const float*)d_in[4];
    const float* Wv   = (const float*)d_in[5];
    const float* Wbw  = (const float*)d_in[6];
    const float* Wbb  = (const float*)d_in[7];
    const float* Waw  = (const float*)d_in[8];
    const float* Wab  = (const float*)d_in[9];
    const float* cw   = (const float*)d_in[10];
    const float* ew   = (const float*)d_in[11];
    const float* ow   = (const float*)d_in[12];
    const float* ob   = (const float*)d_in[13];
    const float* lnqw = (const float*)d_in[14];
    const float* lnqb = (const float*)d_in[15];
    const float* lnkw = (const float*)d_in[16];
    const float* lnkb = (const float*)d_in[17];
    float* out = (float*)d_out;

    float* ws = (float*)d_ws;
    float* q_ws     = ws;                    // 8,388,608 floats
    float* k_ws     = q_ws + 8388608;
    float* v_ws     = k_ws + 8388608;
    float* beta_ws  = v_ws + 8388608;        // 524,288
    float* alpha_ws = beta_ws + 524288;
    float* o_ws     = alpha_ws + 524288;     // 8,388,608

    short* wimg  = (short*)o_ws;             // 106,496 shorts
    short* owimg = (short*)q_ws;             // 24,576 shorts
    float* pq_ws  = out;                     // 256*15*512 floats
    float* min_ws = out + 1966080;           // 256*16*256 floats

    prep_w_kernel<<<26, 256, 0, stream>>>(Wq, Wk, Wv, Wbw, Waw, wimg);
    proj_kernel<<<2048, 256, 0, stream>>>(x, curv, ent, wimg, Wbb, Wab,
                                          cw, ew, lnqw, lnqb, lnkw, lnkb,
                                          q_ws, k_ws, v_ws, beta_ws, alpha_ws);
    scan_p1_kernel<<<dim3(15, 256), 64, 0, stream>>>(k_ws, v_ws, beta_ws, alpha_ws, pq_ws);
    scan_p2_kernel<<<256, 64, 0, stream>>>(pq_ws, min_ws);
    scan_p3_kernel<<<dim3(16, 256), 64, 0, stream>>>(q_ws, k_ws, v_ws, beta_ws, alpha_ws,
                                                     min_ws, o_ws);
    prep_ow_kernel<<<6, 256, 0, stream>>>(ow, owimg);
    outproj_kernel<<<2048, 256, 0, stream>>>(o_ws, owimg, ob, out);
}

// Round 5
// 471.052 us; speedup vs baseline: 1.0959x; 1.0959x over previous
//
#include <hip/hip_runtime.h>

#define TDIM 2048
#define SEGN 32          // p3 segments
#define SEGL 64          // segment length

typedef __attribute__((ext_vector_type(8))) short short8;
typedef __attribute__((ext_vector_type(4))) short short4v;
typedef __attribute__((ext_vector_type(4))) float float4v;

__device__ __forceinline__ float sigf(float x) { return 1.0f / (1.0f + __expf(-x)); }

__device__ __forceinline__ unsigned short f2bf_rne(float f) {
    unsigned u = __float_as_uint(f);
    unsigned r = (u + 0x7fffu + ((u >> 16) & 1u)) >> 16;
    return (unsigned short)r;
}
__device__ __forceinline__ float bf2f(unsigned short h) {
    return __uint_as_float(((unsigned)h) << 16);
}
struct bfpair { short hi, lo; };
__device__ __forceinline__ bfpair cvt_split(float x) {
    bfpair p;
    unsigned short h = f2bf_rne(x);
    p.hi = (short)h;
    p.lo = (short)f2bf_rne(x - bf2f(h));
    return p;
}

// fast split via v_cvt_pk_bf16_f32 (RNE, bit-identical to f2bf_rne)
__device__ __forceinline__ void split4_fast(float4 v, short4v& hi, short4v& lo) {
    unsigned h01, h23;
    asm("v_cvt_pk_bf16_f32 %0, %1, %2" : "=v"(h01) : "v"(v.x), "v"(v.y));
    asm("v_cvt_pk_bf16_f32 %0, %1, %2" : "=v"(h23) : "v"(v.z), "v"(v.w));
    float rx = v.x - __uint_as_float(h01 << 16);
    float ry = v.y - __uint_as_float(h01 & 0xffff0000u);
    float rz = v.z - __uint_as_float(h23 << 16);
    float rw = v.w - __uint_as_float(h23 & 0xffff0000u);
    unsigned l01, l23;
    asm("v_cvt_pk_bf16_f32 %0, %1, %2" : "=v"(l01) : "v"(rx), "v"(ry));
    asm("v_cvt_pk_bf16_f32 %0, %1, %2" : "=v"(l23) : "v"(rz), "v"(rw));
    union { unsigned u[2]; short4v s; } uh, ul;
    uh.u[0] = h01; uh.u[1] = h23;
    ul.u[0] = l01; ul.u[1] = l23;
    hi = uh.s; lo = ul.s;
}

// DPP 16-lane butterfly sum (== shfl_xor 1/2/4/8 tree)
template<int CTRL>
__device__ __forceinline__ float dpp_addt(float v) {
    int t = __builtin_amdgcn_update_dpp(0, __float_as_int(v), CTRL, 0xf, 0xf, true);
    return v + __int_as_float(t);
}
__device__ __forceinline__ float red16d(float v) {
    v = dpp_addt<0xB1>(v);
    v = dpp_addt<0x4E>(v);
    v = dpp_addt<0x141>(v);
    v = dpp_addt<0x140>(v);
    return v;
}

__device__ __forceinline__ float dot4f(float4 a, float4 b) {
    return fmaf(a.w, b.w, fmaf(a.z, b.z, fmaf(a.y, b.y, a.x * b.x)));
}
__device__ __forceinline__ float red4g(float v) {
    v += __shfl_xor(v, 16);
    v += __shfl_xor(v, 32);
    return v;
}

// async global->LDS 16B copy; LDS dest is wave-uniform base + lane*16.
__device__ __forceinline__ void gld16(const void* g, void* l) {
    __builtin_amdgcn_global_load_lds(
        (const __attribute__((address_space(1))) unsigned*)g,
        (__attribute__((address_space(3))) unsigned*)l, 16, 0, 0);
}

// ---------------------------------------------------------------------------
// prep_w: pre-split W (200x256, zero-pad to 208 rows) into SWIZZLED image:
// [kc][row][unit_sw], unit_sw = (2*gg) ^ (row&7) (hi), ^1 (lo).
// ---------------------------------------------------------------------------
__global__ __launch_bounds__(256) void prep_w_kernel(
    const float* __restrict__ Wq, const float* __restrict__ Wk, const float* __restrict__ Wv,
    const float* __restrict__ Wbw, const float* __restrict__ Waw,
    short* __restrict__ wimg)
{
    int u = blockIdx.x * 256 + threadIdx.x;
    if (u >= 6656) return;
    int kc = u / 1664, rem = u % 1664;
    int rr = rem >> 3, gg = rem & 7;
    const float* wrow = nullptr;
    if (rr < 64)       wrow = Wq  + (size_t)rr * 256;
    else if (rr < 128) wrow = Wk  + (size_t)(rr - 64) * 256;
    else if (rr < 192) wrow = Wv  + (size_t)(rr - 128) * 256;
    else if (rr < 196) wrow = Wbw + (size_t)(rr - 192) * 256;
    else if (rr < 200) wrow = Waw + (size_t)(rr - 196) * 256;
    int usw = (2 * gg) ^ (rr & 7);
    short* dh = wimg + ((size_t)kc * 3328 + rr * 16 + usw) * 8;
    short* dl = wimg + ((size_t)kc * 3328 + rr * 16 + (usw ^ 1)) * 8;
#pragma unroll
    for (int s = 0; s < 8; ++s) {
        float v = wrow ? wrow[kc * 64 + gg * 8 + s] : 0.0f;
        bfpair p = cvt_split(v);
        dh[s] = p.hi; dl[s] = p.lo;
    }
}

// prep_ow: out_w (192x64) -> swizzled image [row][unit_sw].
__global__ __launch_bounds__(256) void prep_ow_kernel(
    const float* __restrict__ ow, short* __restrict__ owimg)
{
    int u = blockIdx.x * 256 + threadIdx.x;
    if (u >= 1536) return;
    int rr = u >> 3, gg = u & 7;
    int usw = (2 * gg) ^ (rr & 7);
    short* dh = owimg + ((size_t)rr * 16 + usw) * 8;
    short* dl = owimg + ((size_t)rr * 16 + (usw ^ 1)) * 8;
#pragma unroll
    for (int s = 0; s < 8; ++s) {
        bfpair p = cvt_split(ow[(size_t)rr * 64 + gg * 8 + s]);
        dh[s] = p.hi; dl[s] = p.lo;
    }
}

// ---------------------------------------------------------------------------
// Kernel A: projection GEMM + epilogue. BM=128, 512 threads (2 row-groups x
// 4 nt-groups): halves per-CU W restaging vs BM=64. Half-kc (32-k) slabs.
// ---------------------------------------------------------------------------
__global__ __launch_bounds__(512, 4) void proj_kernel(
    const float* __restrict__ x, const float* __restrict__ curv, const float* __restrict__ ent,
    const short* __restrict__ wimg,
    const float* __restrict__ Wbb, const float* __restrict__ Wab,
    const float* __restrict__ cw, const float* __restrict__ ew,
    const float* __restrict__ lnqw, const float* __restrict__ lnqb,
    const float* __restrict__ lnkw, const float* __restrict__ lnkb,
    float* __restrict__ q_ws, float* __restrict__ k_ws, float* __restrict__ v_ws,
    float* __restrict__ beta_ws, float* __restrict__ alpha_ws)
{
    __shared__ __align__(16) short xsh[128 * 64];     // 16KB
    __shared__ __align__(16) short wsh[1664 * 8];     // 26KB

    const int tid = threadIdx.x;
    const int lane = tid & 63, wv = tid >> 6;
    const int i16 = lane & 15, gq = lane >> 4, swz = i16 & 7;
    const int row0 = blockIdx.x * 128;
    const int wr = wv >> 2, wc = wv & 3;
    const int ntbase = (wc == 0) ? 0 : (1 + 3 * wc);   // 0,4,7,10
    const int ntcnt  = (wc == 0) ? 4 : 3;

    float4v acc[4][4];
#pragma unroll
    for (int m = 0; m < 4; ++m)
#pragma unroll
        for (int nI = 0; nI < 4; ++nI) acc[m][nI] = (float4v){0.f, 0.f, 0.f, 0.f};

    // initial X load (hc=0): 2 float4/thread covering 128 rows x 32 k
    float4 xr[2];
#pragma unroll
    for (int it = 0; it < 2; ++it) {
        int f = it * 512 + tid, rr = f >> 3, c4 = f & 7;
        xr[it] = *(const float4*)&x[(size_t)(row0 + rr) * 256 + c4 * 4];
    }

    for (int hc = 0; hc < 8; ++hc) {
        __builtin_amdgcn_s_barrier();            // previous MFMA done; LDS free
        // W half-slab async stage: 1664 units, 4 guarded iters x 512 thr
        const short* wk = wimg + (size_t)(hc >> 1) * 26624;
        const int hoff = (hc & 1) * 8;
#pragma unroll
        for (int it = 0; it < 4; ++it) {
            int f = it * 512 + tid;
            if (f < 1664) {
                int rr = f >> 3, uu = f & 7;
                gld16(wk + ((size_t)rr * 16 + hoff + uu) * 8, &wsh[f * 8]);
            }
        }
        asm volatile("" ::: "memory");
        // X convert current half (xr resident)
#pragma unroll
        for (int it = 0; it < 2; ++it) {
            int f = it * 512 + tid, rr = f >> 3, c4 = f & 7;
            short4v hi, lo;
            split4_fast(xr[it], hi, lo);
            int usw = (2 * (c4 >> 1)) ^ (rr & 7);
            *(short4v*)&xsh[rr * 64 + usw * 8 + (c4 & 1) * 4] = hi;
            *(short4v*)&xsh[rr * 64 + (usw ^ 1) * 8 + (c4 & 1) * 4] = lo;
        }
        // prefetch next half's X (in flight across the barrier)
        if (hc < 7) {
#pragma unroll
            for (int it = 0; it < 2; ++it) {
                int f = it * 512 + tid, rr = f >> 3, c4 = f & 7;
                xr[it] = *(const float4*)&x[(size_t)(row0 + rr) * 256 + (hc + 1) * 32 + c4 * 4];
            }
            asm volatile("s_waitcnt vmcnt(2) lgkmcnt(0)" ::: "memory");
        } else {
            asm volatile("s_waitcnt vmcnt(0) lgkmcnt(0)" ::: "memory");
        }
        __builtin_amdgcn_s_barrier();
        // MFMA phase
        const int uA = ((2 * gq) ^ swz) * 8;
        short8 ah[4], al[4];
#pragma unroll
        for (int m = 0; m < 4; ++m) {
            const int rb = (wr * 64 + m * 16 + i16) * 64;
            ah[m] = *(const short8*)&xsh[rb + uA];
            al[m] = *(const short8*)&xsh[rb + (uA ^ 8)];
        }
#pragma unroll
        for (int nI = 0; nI < 4; ++nI) if (nI < ntcnt) {
            const int rowB = ((ntbase + nI) * 16 + i16) * 64;
            short8 bh = *(const short8*)&wsh[rowB + uA];
            short8 bl = *(const short8*)&wsh[rowB + (uA ^ 8)];
#pragma unroll
            for (int m = 0; m < 4; ++m) {
                acc[m][nI] = __builtin_amdgcn_mfma_f32_16x16x32_bf16(ah[m], bh, acc[m][nI], 0, 0, 0);
                acc[m][nI] = __builtin_amdgcn_mfma_f32_16x16x32_bf16(ah[m], bl, acc[m][nI], 0, 0, 0);
                acc[m][nI] = __builtin_amdgcn_mfma_f32_16x16x32_bf16(al[m], bh, acc[m][nI], 0, 0, 0);
            }
        }
    }

    // Epilogue. C/D layout: col = lane&15, row = (lane>>4)*4 + reg.
    const int c = i16;
    const float lnqw_c = lnqw[c], lnqb_c = lnqb[c];
    const float lnkw_c = lnkw[c], lnkb_c = lnkb[c];
    const int nblk = row0 >> 11;
    const float Kv = fminf(fabsf(curv[nblk >> 4]), 10.0f);
    const float Sv = fminf(fmaxf(ent[nblk >> 4], 0.0f), 5.0f);
#pragma unroll
    for (int nI = 0; nI < 4; ++nI) if (nI < ntcnt) {
        const int nt = ntbase + nI;
#pragma unroll
        for (int m = 0; m < 4; ++m) {
#pragma unroll
            for (int j = 0; j < 4; ++j) {
                const int grow = row0 + wr * 64 + m * 16 + gq * 4 + j;
                const int n = grow >> 11, t = grow & 2047;
                float y = acc[m][nI][j];
                if (nt < 4) {
                    float s = red16d(y), s2 = red16d(y * y);
                    float mean = s * 0.0625f;
                    float var = s2 * 0.0625f - mean * mean;
                    float inv = rsqrtf(var + 1e-5f);
                    q_ws[((size_t)(n * 4 + nt) * TDIM + t) * 16 + c] = (y - mean) * inv * lnqw_c + lnqb_c;
                } else if (nt < 8) {
                    float s = red16d(y), s2 = red16d(y * y);
                    float mean = s * 0.0625f;
                    float var = s2 * 0.0625f - mean * mean;
                    float inv = rsqrtf(var + 1e-5f);
                    float kn = (y - mean) * inv * lnkw_c + lnkb_c;
                    float s3 = red16d(kn * kn);
                    kn = kn / fmaxf(sqrtf(s3), 1e-12f);
                    k_ws[((size_t)(n * 4 + (nt - 4)) * TDIM + t) * 16 + c] = kn;
                } else if (nt < 12) {
                    v_ws[((size_t)(n * 4 + (nt - 8)) * TDIM + t) * 16 + c] = y;
                } else {
                    if (c < 4)
                        beta_ws[(size_t)(n * 4 + c) * TDIM + t] = sigf(sigf(y + Wbb[c]) + Kv * cw[c]);
                    else if (c < 8) {
                        int h = c - 4;
                        alpha_ws[(size_t)(n * 4 + h) * TDIM + t] = sigf(sigf(y + Wab[h]) + Sv * ew[h]);
                    }
                }
            }
        }
    }
}

// ---------------------------------------------------------------------------
// Segmented scan, SEGL=64. Buffers are 68 rows with +2 offset: rows 0,1 are
// the zeroed k_{-1},k_{-2} guard, rows 2..65 hold t=0..63, rows 66,67 are the
// zeroed look-ahead guard. No ring-mod; machinery otherwise identical to the
// verified SEGLEN=128 version.
// ---------------------------------------------------------------------------

// Phase 1: per (chain, segment 0..30) compute transfer (P,Q).
__global__ __launch_bounds__(64) void scan_p1_kernel(
    const float* __restrict__ k_ws, const float* __restrict__ v_ws,
    const float* __restrict__ beta_ws, const float* __restrict__ alpha_ws,
    float* __restrict__ pq_ws)
{
    __shared__ __align__(16) float ks[68 * 16], bvs[68 * 16];
    __shared__ __align__(16) float tb1[68 * 4];
    const int tid = threadIdx.x;
    const int sid = blockIdx.x;     // 0..30
    const int cid = blockIdx.y;     // 0..255
    const int i = tid & 15, g = tid >> 4;
    const int t0g = sid * SEGL;
    const float* kb = k_ws + ((size_t)cid * TDIM + t0g) * 16;
    const float* vb = v_ws + ((size_t)cid * TDIM + t0g) * 16;
    const float* bb = beta_ws + (size_t)cid * TDIM + t0g;
    const float* ab = alpha_ws + (size_t)cid * TDIM + t0g;

    for (int f = tid; f < 68 * 16; f += 64) { ks[f] = 0.f; bvs[f] = 0.f; }
    for (int f = tid; f < 68 * 4; f += 64) tb1[f] = 0.f;
    __syncthreads();

    // stage t = tid into row tid+2
    {
        const float4* kp = (const float4*)(kb + (size_t)tid * 16);
        const float4* vp = (const float4*)(vb + (size_t)tid * 16);
        float be = bb[tid];
        int r = tid + 2;
#pragma unroll
        for (int j = 0; j < 4; ++j) {
            float4 kv = kp[j];
            float4 vv = vp[j];
            *(float4*)&ks[r * 16 + 4 * j] = kv;
            float4 bv4 = make_float4(be * vv.x, be * vv.y, be * vv.z, be * vv.w);
            *(float4*)&bvs[r * 16 + 4 * j] = bv4;
        }
    }
    float alp = ab[tid];
    __syncthreads();
    // table pass: row r0 = tid+2 (t = tid)
    {
        int r0 = tid + 2, rm1 = tid + 1, rm2 = tid;
        float C = 0.f, C2 = 0.f;
#pragma unroll
        for (int j = 0; j < 4; ++j) {
            float4 kt  = *(float4*)&ks[r0 * 16 + 4 * j];
            float4 km1 = *(float4*)&ks[rm1 * 16 + 4 * j];
            float4 km2 = *(float4*)&ks[rm2 * 16 + 4 * j];
            C  += dot4f(km1, kt);
            C2 += dot4f(km2, kt);
        }
        *(float4*)&tb1[r0 * 4] = make_float4(alp * C, alp * C2, alp, 0.f);
    }
    __syncthreads();

    // dual state: Q rows (init 0, source bv), P rows (init I, source 0)
    float4 Q4 = make_float4(0.f, 0.f, 0.f, 0.f);
    float4 P4 = make_float4(i == 4 * g + 0 ? 1.f : 0.f,
                            i == 4 * g + 1 ? 1.f : 0.f,
                            i == 4 * g + 2 ? 1.f : 0.f,
                            i == 4 * g + 3 ? 1.f : 0.f);
    float wq1 = 0.f, wq2 = 0.f, wp1 = 0.f, wp2 = 0.f;
    float4 k4m1 = make_float4(0.f, 0.f, 0.f, 0.f);
    float4 k4_0 = *(float4*)&ks[2 * 16 + 4 * g];
    float4 k4p1 = *(float4*)&ks[3 * 16 + 4 * g];
    float upQ_cur = 0.f;
    float upP_cur = ks[2 * 16 + i];          // (I k0)[i]
    float4 ta0 = *(float4*)&tb1[2 * 4];
    float aC1_c = ta0.x, aC2_c = ta0.y, al_c = ta0.z;
    float bv_c = bvs[2 * 16 + i];

    int t = 0;
    auto step = [&]() {
        int rin = t + 4, rtb = t + 3;        // guard rows 66,67 are zero
        float4 k4in = *(float4*)&ks[rin * 16 + 4 * g];
        float4 tain = *(float4*)&tb1[rtb * 4];
        float bvin = bvs[rtb * 16 + i];
        float upQ = red4g(dot4f(Q4, k4p1));
        float upP = red4g(dot4f(P4, k4p1));
        Q4.x = fmaf(wq1, k4m1.x, Q4.x);
        Q4.y = fmaf(wq1, k4m1.y, Q4.y);
        Q4.z = fmaf(wq1, k4m1.z, Q4.z);
        Q4.w = fmaf(wq1, k4m1.w, Q4.w);
        P4.x = fmaf(wp1, k4m1.x, P4.x);
        P4.y = fmaf(wp1, k4m1.y, P4.y);
        P4.z = fmaf(wp1, k4m1.z, P4.z);
        P4.w = fmaf(wp1, k4m1.w, P4.w);
        float rq = fmaf(-aC2_c, wq2, fmaf(-al_c, upQ_cur, bv_c));
        float wq0 = fmaf(-aC1_c, wq1, rq);
        float rp_ = fmaf(-aC2_c, wp2, -al_c * upP_cur);
        float wp0 = fmaf(-aC1_c, wp1, rp_);
        wq2 = wq1; wq1 = wq0; wp2 = wp1; wp1 = wp0;
        k4m1 = k4_0; k4_0 = k4p1; k4p1 = k4in;
        upQ_cur = upQ; upP_cur = upP;
        aC1_c = tain.x; aC2_c = tain.y; al_c = tain.z; bv_c = bvin;
        ++t;
    };

#pragma unroll 4
    for (int u = 0; u < 64; ++u) step();

    // finalize lag: state = M_{62}; add w_{63} k_{63}
    Q4.x = fmaf(wq1, k4m1.x, Q4.x);
    Q4.y = fmaf(wq1, k4m1.y, Q4.y);
    Q4.z = fmaf(wq1, k4m1.z, Q4.z);
    Q4.w = fmaf(wq1, k4m1.w, Q4.w);
    P4.x = fmaf(wp1, k4m1.x, P4.x);
    P4.y = fmaf(wp1, k4m1.y, P4.y);
    P4.z = fmaf(wp1, k4m1.z, P4.z);
    P4.w = fmaf(wp1, k4m1.w, P4.w);

    float* dst = pq_ws + ((size_t)cid * 31 + sid) * 512;
    *(float4*)&dst[i * 16 + 4 * g] = Q4;
    *(float4*)&dst[256 + i * 16 + 4 * g] = P4;
}

// Phase 2: fold M_in across 31 segments.
__global__ __launch_bounds__(64) void scan_p2_kernel(
    const float* __restrict__ pq_ws, float* __restrict__ min_ws)
{
    __shared__ float Mlds[256], Plds[256];
    const int tid = threadIdx.x;
    const int cid = blockIdx.x;
    const int i = tid & 15, g = tid >> 4;
    float4 M4 = make_float4(0.f, 0.f, 0.f, 0.f);
    *(float4*)&min_ws[((size_t)cid * SEGN + 0) * 256 + i * 16 + 4 * g] = M4;
    for (int sid = 0; sid < 31; ++sid) {
        const float* base = pq_ws + ((size_t)cid * 31 + sid) * 512;
        float4 Qn = *(const float4*)&base[i * 16 + 4 * g];
        float4 Pn = *(const float4*)&base[256 + i * 16 + 4 * g];
        *(float4*)&Mlds[i * 16 + 4 * g] = M4;
        *(float4*)&Plds[i * 16 + 4 * g] = Pn;
        __syncthreads();
        float4 acc = Qn;
#pragma unroll
        for (int m = 0; m < 16; ++m) {
            float mm = Mlds[i * 16 + m];
            float4 pr = *(float4*)&Plds[m * 16 + 4 * g];
            acc.x = fmaf(mm, pr.x, acc.x);
            acc.y = fmaf(mm, pr.y, acc.y);
            acc.z = fmaf(mm, pr.z, acc.z);
            acc.w = fmaf(mm, pr.w, acc.w);
        }
        M4 = acc;
        __syncthreads();
        *(float4*)&min_ws[((size_t)cid * SEGN + sid + 1) * 256 + i * 16 + 4 * g] = M4;
    }
}

// Phase 3: delta-rule machinery per (chain, segment 0..31), primed with M_in.
__global__ __launch_bounds__(64) void scan_p3_kernel(
    const float* __restrict__ q_ws, const float* __restrict__ k_ws, const float* __restrict__ v_ws,
    const float* __restrict__ beta_ws, const float* __restrict__ alpha_ws,
    const float* __restrict__ min_ws, float* __restrict__ o_ws)
{
    __shared__ __align__(16) float ks[68 * 16], qs[68 * 16], bvs[68 * 16];
    __shared__ __align__(16) float tbl[68 * 8];
    __shared__ __align__(16) float os[64 * 16];
    const int tid = threadIdx.x;
    const int sid = blockIdx.x;     // 0..31
    const int cid = blockIdx.y;     // 0..255
    const int i = tid & 15, g = tid >> 4;
    const int t0g = sid * SEGL;
    const float* kb = k_ws + ((size_t)cid * TDIM + t0g) * 16;
    const float* qb = q_ws + ((size_t)cid * TDIM + t0g) * 16;
    const float* vb = v_ws + ((size_t)cid * TDIM + t0g) * 16;
    const float* bb = beta_ws + (size_t)cid * TDIM + t0g;
    const float* ab = alpha_ws + (size_t)cid * TDIM + t0g;
    float* obp = o_ws + ((size_t)cid * TDIM + t0g) * 16;

    for (int f = tid; f < 68 * 16; f += 64) { ks[f] = 0.f; qs[f] = 0.f; bvs[f] = 0.f; }
    for (int f = tid; f < 68 * 8; f += 64) tbl[f] = 0.f;
    __syncthreads();

    // stage t = tid into row tid+2
    {
        const float4* kp = (const float4*)(kb + (size_t)tid * 16);
        const float4* qp = (const float4*)(qb + (size_t)tid * 16);
        const float4* vp = (const float4*)(vb + (size_t)tid * 16);
        float be = bb[tid];
        int r = tid + 2;
#pragma unroll
        for (int j = 0; j < 4; ++j) {
            float4 kv = kp[j];
            float4 qv = qp[j];
            float4 vv = vp[j];
            *(float4*)&ks[r * 16 + 4 * j] = kv;
            *(float4*)&qs[r * 16 + 4 * j] = qv;
            float4 bv4 = make_float4(be * vv.x, be * vv.y, be * vv.z, be * vv.w);
            *(float4*)&bvs[r * 16 + 4 * j] = bv4;
        }
    }
    float alp = ab[tid];
    __syncthreads();
    {
        int r0 = tid + 2, rm1 = tid + 1, rm2 = tid;
        float C = 0.f, C2 = 0.f, d = 0.f, e = 0.f, E2 = 0.f;
#pragma unroll
        for (int j = 0; j < 4; ++j) {
            float4 kt  = *(float4*)&ks[r0 * 16 + 4 * j];
            float4 km1 = *(float4*)&ks[rm1 * 16 + 4 * j];
            float4 km2 = *(float4*)&ks[rm2 * 16 + 4 * j];
            float4 qt  = *(float4*)&qs[r0 * 16 + 4 * j];
            C  += dot4f(km1, kt);
            C2 += dot4f(km2, kt);
            d  += dot4f(kt,  qt);
            e  += dot4f(km1, qt);
            E2 += dot4f(km2, qt);
        }
        *(float4*)&tbl[r0 * 8] = make_float4(alp * C, alp * C2, d, e);
        *(float2*)&tbl[r0 * 8 + 4] = make_float2(E2, alp);
    }
    __syncthreads();

    // prime with exact M_in = M_{t0-1}
    float4 M4 = *(const float4*)&min_ws[((size_t)cid * SEGN + sid) * 256 + i * 16 + 4 * g];
    float w1 = 0.f, w2 = 0.f;
    float4 k4m1 = make_float4(0.f, 0.f, 0.f, 0.f);
    float4 k4_0 = *(float4*)&ks[2 * 16 + 4 * g];
    float4 q4_0 = *(float4*)&qs[2 * 16 + 4 * g];
    float4 k4p1 = *(float4*)&ks[3 * 16 + 4 * g];
    float4 q4p1 = *(float4*)&qs[3 * 16 + 4 * g];
    float up_cur = red4g(dot4f(M4, k4_0));   // M_in . k_{t0}
    float rp_cur = red4g(dot4f(M4, q4_0));   // M_in . q_{t0}
    float4 ta0 = *(float4*)&tbl[2 * 8];
    float aC1_c = ta0.x, aC2_c = ta0.y, d_c = ta0.z, e_c = ta0.w;
    float2 tx0 = *(float2*)&tbl[2 * 8 + 4];
    float E2_c = tx0.x, al_c = tx0.y;
    float bv_c = bvs[2 * 16 + i];

    int t = 0;
    auto step = [&]() {
        int rin = t + 4, rtb = t + 3;
        float4 k4in = *(float4*)&ks[rin * 16 + 4 * g];
        float4 q4in = *(float4*)&qs[rin * 16 + 4 * g];
        float4 tain = *(float4*)&tbl[rtb * 8];
        float2 txin = *(float2*)&tbl[rtb * 8 + 4];
        float bvin = bvs[rtb * 16 + i];
        float up = red4g(dot4f(M4, k4p1));
        float rp = red4g(dot4f(M4, q4p1));
        M4.x = fmaf(w1, k4m1.x, M4.x);
        M4.y = fmaf(w1, k4m1.y, M4.y);
        M4.z = fmaf(w1, k4m1.z, M4.z);
        M4.w = fmaf(w1, k4m1.w, M4.w);
        float r = fmaf(-aC2_c, w2, fmaf(-al_c, up_cur, bv_c));
        float w0 = fmaf(-aC1_c, w1, r);
        float o = fmaf(w0, d_c, fmaf(w1, e_c, fmaf(w2, E2_c, rp_cur)));
        if (g == 0) os[t * 16 + i] = o;
        w2 = w1; w1 = w0;
        k4m1 = k4_0; k4_0 = k4p1; k4p1 = k4in;
        q4p1 = q4in;
        up_cur = up; rp_cur = rp;
        aC1_c = tain.x; aC2_c = tain.y; d_c = tain.z; e_c = tain.w;
        E2_c = txin.x; al_c = txin.y; bv_c = bvin;
        ++t;
    };

#pragma unroll 4
    for (int u = 0; u < 64; ++u) step();

    // flush (single wave; DS in-order -> os writes visible)
#pragma unroll
    for (int j = 0; j < 4; ++j) {
        float4 ov = *(float4*)&os[(tid * 4 + j) * 4];
        *(float4*)&obp[(tid * 4 + j) * 4] = ov;
    }
}

// ---------------------------------------------------------------------------
// Kernel C: output projection, BM=128, 512 threads, half-K slabs.
// ---------------------------------------------------------------------------
__global__ __launch_bounds__(512, 4) void outproj_kernel(
    const float* __restrict__ o_ws, const short* __restrict__ owimg,
    const float* __restrict__ ob, float* __restrict__ out)
{
    __shared__ __align__(16) short osh[128 * 64];     // 16KB
    __shared__ __align__(16) short wsh[1536 * 8];     // 24KB
    const int tid = threadIdx.x;
    const int lane = tid & 63, wv = tid >> 6;
    const int i16 = lane & 15, gq = lane >> 4, swz = i16 & 7;
    const int row0 = blockIdx.x * 128;
    const int wr = wv >> 2, wc = wv & 3;
    const int ntbase = wc * 3;

    float4v acc[4][3];
#pragma unroll
    for (int m = 0; m < 4; ++m)
#pragma unroll
        for (int nI = 0; nI < 3; ++nI) acc[m][nI] = (float4v){0.f, 0.f, 0.f, 0.f};

    // initial o load (half 0)
    float4 orr[2];
#pragma unroll
    for (int it = 0; it < 2; ++it) {
        int f = it * 512 + tid, rr = f >> 3, c4 = f & 7;
        int grow = row0 + rr;
        int n = grow >> 11, t = grow & 2047;
        int h = c4 >> 2, d4 = c4 & 3;
        orr[it] = *(const float4*)&o_ws[((size_t)(n * 4 + h) * TDIM + t) * 16 + d4 * 4];
    }

#pragma unroll
    for (int half = 0; half < 2; ++half) {
        __builtin_amdgcn_s_barrier();
        // W half-slab async stage: 1536 units = 3 iters x 512
#pragma unroll
        for (int it = 0; it < 3; ++it) {
            int f = it * 512 + tid;
            int rr = f >> 3, uu = f & 7;
            gld16(owimg + ((size_t)rr * 16 + half * 8 + uu) * 8, &wsh[f * 8]);
        }
        asm volatile("" ::: "memory");
        // o convert current half
#pragma unroll
        for (int it = 0; it < 2; ++it) {
            int f = it * 512 + tid, rr = f >> 3, c4 = f & 7;
            short4v hi, lo;
            split4_fast(orr[it], hi, lo);
            int usw = (2 * (c4 >> 1)) ^ (rr & 7);
            *(short4v*)&osh[rr * 64 + usw * 8 + (c4 & 1) * 4] = hi;
            *(short4v*)&osh[rr * 64 + (usw ^ 1) * 8 + (c4 & 1) * 4] = lo;
        }
        if (half == 0) {
#pragma unroll
            for (int it = 0; it < 2; ++it) {
                int f = it * 512 + tid, rr = f >> 3, c4 = f & 7;
                int grow = row0 + rr;
                int n = grow >> 11, t = grow & 2047;
                int col = 32 + c4 * 4;
                int h = col >> 4, d4 = (col >> 2) & 3;
                orr[it] = *(const float4*)&o_ws[((size_t)(n * 4 + h) * TDIM + t) * 16 + d4 * 4];
            }
            asm volatile("s_waitcnt vmcnt(2) lgkmcnt(0)" ::: "memory");
        } else {
            asm volatile("s_waitcnt vmcnt(0) lgkmcnt(0)" ::: "memory");
        }
        __builtin_amdgcn_s_barrier();

        const int uA = ((2 * gq) ^ swz) * 8;
        short8 ah[4], al[4];
#pragma unroll
        for (int m = 0; m < 4; ++m) {
            const int rb = (wr * 64 + m * 16 + i16) * 64;
            ah[m] = *(const short8*)&osh[rb + uA];
            al[m] = *(const short8*)&osh[rb + (uA ^ 8)];
        }
#pragma unroll
        for (int nI = 0; nI < 3; ++nI) {
            const int rowB = ((ntbase + nI) * 16 + i16) * 64;
            short8 bh = *(const short8*)&wsh[rowB + uA];
            short8 bl = *(const short8*)&wsh[rowB + (uA ^ 8)];
#pragma unroll
            for (int m = 0; m < 4; ++m) {
                acc[m][nI] = __builtin_amdgcn_mfma_f32_16x16x32_bf16(ah[m], bh, acc[m][nI], 0, 0, 0);
                acc[m][nI] = __builtin_amdgcn_mfma_f32_16x16x32_bf16(ah[m], bl, acc[m][nI], 0, 0, 0);
                acc[m][nI] = __builtin_amdgcn_mfma_f32_16x16x32_bf16(al[m], bh, acc[m][nI], 0, 0, 0);
            }
        }
    }

#pragma unroll
    for (int nI = 0; nI < 3; ++nI) {
        const int nt = ntbase + nI;
        const float bias = ob[nt * 16 + i16];
#pragma unroll
        for (int m = 0; m < 4; ++m) {
#pragma unroll
            for (int j = 0; j < 4; ++j) {
                int grow = row0 + wr * 64 + m * 16 + gq * 4 + j;
                int n = grow >> 11, t = grow & 2047;
                int b = n >> 4, p = n & 15;
                out[((size_t)(b * TDIM + t) * 16 + p) * 192 + nt * 16 + i16] = acc[m][nI][j] + bias;
            }
        }
    }
}

extern "C" void kernel_launch(void* const* d_in, const int* in_sizes, int n_in,
                              void* d_out, int out_size, void* d_ws, size_t ws_size,
                              hipStream_t stream) {
    (void)in_sizes; (void)n_in; (void)out_size; (void)ws_size;
    const float* x    = (const float*)d_in[0];
    const float* curv = (const float*)d_in[1];
    const float* ent  = (const float*)d_in[2];
    const float* Wq   = (const float*)d_in[3];
    const float* Wk   = (const float*)d_in[4];
    const float* Wv   = (const float*)d_in[5];
    const float* Wbw  = (const float*)d_in[6];
    const float* Wbb  = (const float*)d_in[7];
    const float* Waw  = (const float*)d_in[8];
    const float* Wab  = (const float*)d_in[9];
    const float* cw   = (const float*)d_in[10];
    const float* ew   = (const float*)d_in[11];
    const float* ow   = (const float*)d_in[12];
    const float* ob   = (const float*)d_in[13];
    const float* lnqw = (const float*)d_in[14];
    const float* lnqb = (const float*)d_in[15];
    const float* lnkw = (const float*)d_in[16];
    const float* lnkb = (const float*)d_in[17];
    float* out = (float*)d_out;

    float* ws = (float*)d_ws;
    float* q_ws     = ws;                    // 8,388,608 floats
    float* k_ws     = q_ws + 8388608;
    float* v_ws     = k_ws + 8388608;
    float* beta_ws  = v_ws + 8388608;        // 524,288
    float* alpha_ws = beta_ws + 524288;
    float* o_ws     = alpha_ws + 524288;     // 8,388,608

    short* wimg  = (short*)o_ws;             // 106,496 shorts
    short* owimg = (short*)q_ws;             // 24,576 shorts
    float* pq_ws  = out;                     // 256*31*512 = 4,063,232 floats
    float* min_ws = out + 4063232;           // 256*32*256 = 2,097,152 floats

    prep_w_kernel<<<26, 256, 0, stream>>>(Wq, Wk, Wv, Wbw, Waw, wimg);
    proj_kernel<<<1024, 512, 0, stream>>>(x, curv, ent, wimg, Wbb, Wab,
                                          cw, ew, lnqw, lnqb, lnkw, lnkb,
                                          q_ws, k_ws, v_ws, beta_ws, alpha_ws);
    scan_p1_kernel<<<dim3(31, 256), 64, 0, stream>>>(k_ws, v_ws, beta_ws, alpha_ws, pq_ws);
    scan_p2_kernel<<<256, 64, 0, stream>>>(pq_ws, min_ws);
    scan_p3_kernel<<<dim3(32, 256), 64, 0, stream>>>(q_ws, k_ws, v_ws, beta_ws, alpha_ws,
                                                     min_ws, o_ws);
    prep_ow_kernel<<<6, 256, 0, stream>>>(ow, owimg);
    outproj_kernel<<<1024, 512, 0, stream>>>(o_ws, owimg, ob, out);
}